// Round 1
// baseline (23866.771 us; speedup 1.0000x reference)
//
#include <hip/hip_runtime.h>

// Problem dims
#define B_ 32
#define S_ 512
#define D_ 512
#define H_ 256

typedef float floatx4 __attribute__((ext_vector_type(4)));
typedef short short8v __attribute__((ext_vector_type(8)));
typedef unsigned short u16;
typedef unsigned int u32;

#define REC_SMEM_BYTES ((128*257 + 2048 + 4*128*10 + 256) * 4)  // 161280 B < 160 KiB
#define WS_NEEDED 138543360ull

__device__ __forceinline__ u16 f2bf(float f) {
  u32 x = __float_as_uint(f);
  x += 0x7fffu + ((x >> 16) & 1u);   // RNE
  return (u16)(x >> 16);
}
__device__ __forceinline__ float bf2f(u16 h) {
  return __uint_as_float(((u32)h) << 16);
}
__device__ __forceinline__ float sigf(float x) {
  return 1.0f / (1.0f + __expf(-x));
}
__device__ __forceinline__ float tanh_f(float x) {
  float e = __expf(-2.0f * fabsf(x));
  float r = (1.0f - e) / (1.0f + e);
  return copysignf(r, x);
}

struct alignas(16) U16x8 { u16 v[8]; };

// ---------------- embedding -> X0 bf16, time-major (m = s*32+b, 512 feats) ----------------
__global__ void prep_k(const int* __restrict__ ids, const int* __restrict__ amask,
                       const float* __restrict__ emb, u16* __restrict__ X0) {
  int m = blockIdx.x;            // m = s*32 + b
  int lane = threadIdx.x;        // 64
  int s = m >> 5, b = m & 31;
  int id = ids[b * S_ + s];
  int mk = amask[b * S_ + s];
  const float4* src = (const float4*)(emb + (size_t)id * D_) + lane * 2;
  float4 v0 = src[0], v1 = src[1];
  if (!mk) { v0 = make_float4(0,0,0,0); v1 = make_float4(0,0,0,0); }
  U16x8 o;
  o.v[0]=f2bf(v0.x); o.v[1]=f2bf(v0.y); o.v[2]=f2bf(v0.z); o.v[3]=f2bf(v0.w);
  o.v[4]=f2bf(v1.x); o.v[5]=f2bf(v1.y); o.v[6]=f2bf(v1.z); o.v[7]=f2bf(v1.w);
  *(U16x8*)(X0 + (size_t)m * D_ + lane * 8) = o;
}

// ---------------- fp32 -> bf16 weight convert (w_ih, 2*2*1024*512 elems) ----------------
__global__ void conv_k(const float* __restrict__ w, u16* __restrict__ wbf, int n8) {
  int idx = blockIdx.x * blockDim.x + threadIdx.x;
  if (idx >= n8) return;
  const float4* s = (const float4*)w + (size_t)idx * 2;
  float4 v0 = s[0], v1 = s[1];
  U16x8 o;
  o.v[0]=f2bf(v0.x); o.v[1]=f2bf(v0.y); o.v[2]=f2bf(v0.z); o.v[3]=f2bf(v0.w);
  o.v[4]=f2bf(v1.x); o.v[5]=f2bf(v1.y); o.v[6]=f2bf(v1.z); o.v[7]=f2bf(v1.w);
  *(U16x8*)(wbf + (size_t)idx * 8) = o;
}

// ---------------- zero Hbuf / sync counters / loss ----------------
__global__ void zero_k(float* __restrict__ Hb, int* __restrict__ cnt, float* __restrict__ loss) {
  int idx = blockIdx.x * 256 + threadIdx.x;   // grid 128x256 = 32768
  if (idx < 32768) Hb[idx] = 0.f;
  if (idx < 8) cnt[idx] = 0;
  if (idx == 0) *loss = 0.f;
}

// ---------------- bf16 MFMA GEMM: G[m][n] = A[m][:] . W[n][:] + bih[n] + bhh[n] ----------------
// A: (16384, 512) bf16 row-major; W: (2048, 512) bf16 row-major; G: (16384, 2048) bf16
__global__ void gemm_k(const u16* __restrict__ A, const u16* __restrict__ W,
                       const float* __restrict__ bih, const float* __restrict__ bhh,
                       u16* __restrict__ G) {
  __shared__ short Asm[64 * 40];
  __shared__ short Bsm[64 * 40];
  const int tid = threadIdx.x;
  const int m0 = blockIdx.x * 64, n0 = blockIdx.y * 64;
  const int wid = tid >> 6, lane = tid & 63;
  const int quad = lane >> 4, lr = lane & 15;
  const int wm = (wid >> 1) * 32, wn = (wid & 1) * 32;
  const int lrow = tid >> 2, lk = (tid & 3) * 8;
  floatx4 acc00 = {0,0,0,0}, acc01 = {0,0,0,0}, acc10 = {0,0,0,0}, acc11 = {0,0,0,0};
  for (int kt = 0; kt < 16; ++kt) {
    const int k0 = kt * 32;
    uint4 av = *(const uint4*)(A + (size_t)(m0 + lrow) * 512 + k0 + lk);
    uint4 bv = *(const uint4*)(W + (size_t)(n0 + lrow) * 512 + k0 + lk);
    __syncthreads();
    *(uint4*)&Asm[lrow * 40 + lk] = av;
    *(uint4*)&Bsm[lrow * 40 + lk] = bv;
    __syncthreads();
    short8v a0 = *(const short8v*)&Asm[(wm + lr) * 40 + quad * 8];
    short8v a1 = *(const short8v*)&Asm[(wm + 16 + lr) * 40 + quad * 8];
    short8v b0 = *(const short8v*)&Bsm[(wn + lr) * 40 + quad * 8];
    short8v b1 = *(const short8v*)&Bsm[(wn + 16 + lr) * 40 + quad * 8];
    acc00 = __builtin_amdgcn_mfma_f32_16x16x32_bf16(a0, b0, acc00, 0, 0, 0);
    acc01 = __builtin_amdgcn_mfma_f32_16x16x32_bf16(a0, b1, acc01, 0, 0, 0);
    acc10 = __builtin_amdgcn_mfma_f32_16x16x32_bf16(a1, b0, acc10, 0, 0, 0);
    acc11 = __builtin_amdgcn_mfma_f32_16x16x32_bf16(a1, b1, acc11, 0, 0, 0);
  }
  #pragma unroll
  for (int j = 0; j < 2; ++j) {
    const int n = n0 + wn + j * 16 + lr;
    const float bias = bih[n] + bhh[n];
    #pragma unroll
    for (int i = 0; i < 2; ++i) {
      const int mb = m0 + wm + i * 16 + quad * 4;
      floatx4 av = (i == 0) ? (j == 0 ? acc00 : acc01) : (j == 0 ? acc10 : acc11);
      #pragma unroll
      for (int rr = 0; rr < 4; ++rr) {
        G[(size_t)(mb + rr) * 2048 + n] = f2bf(av[rr] + bias);
      }
    }
  }
}

// ---------------- LSTM recurrence, one layer, both dirs ----------------
// grid: 64 blocks = dir(2) x slice(8) x bg(4); 512 threads; Whh slice in LDS (fp32).
// Sync group: the 8 slice-wgs sharing (dir,bg) exchange h via Hbuf + device-scope flag.
__launch_bounds__(512, 1)
__global__ void rec_k(const u16* __restrict__ G, const float* __restrict__ whh_l,
                      float* __restrict__ Hbuf, int* __restrict__ cnt,
                      u16* __restrict__ Xbf, float* __restrict__ Xf) {
  extern __shared__ float smem[];
  float* wlds = smem;                     // [128][257]
  float* hlds = smem + 128 * 257;         // [256][8]
  float* part = hlds + 2048;              // [4][128][10]
  float* clds = part + 4 * 128 * 10;      // [32][8]
  const int tid = threadIdx.x;
  const int dir = blockIdx.x >> 5;
  const int slice = (blockIdx.x >> 2) & 7;
  const int bg = blockIdx.x & 3;
  const float* whh = whh_l + dir * (1024 * 256);
  // Load weight slice: local row r = jj*4 + type  <->  global row = type*256 + slice*32 + jj
  for (int idx = tid; idx < 128 * 256; idx += 512) {
    int r = idx >> 8, k = idx & 255;
    int grow = (r & 3) * 256 + slice * 32 + (r >> 2);
    wlds[r * 257 + k] = whh[grow * 256 + k];
  }
  if (tid < 256) clds[tid] = 0.f;
  int* mycnt = cnt + dir * 4 + bg;
  float* hb = Hbuf + (dir * 4 + bg) * 4096;
  const int kc = tid >> 7;        // k-chunk 0..3
  const int r = tid & 127;        // local gate row
  const int ub = tid >> 5;        // updater: batch in group (tid<256)
  const int ujj = tid & 31;       // updater: hidden within slice
  __syncthreads();
  for (int q = 0; q < 512; ++q) {
    const int t = dir ? (511 - q) : q;
    const int par = q & 1;
    if (q > 0) {
      if (tid == 0) {
        const int target = 8 * q;
        int guard = 0;
        while (__hip_atomic_load(mycnt, __ATOMIC_ACQUIRE, __HIP_MEMORY_SCOPE_AGENT) < target) {
          if (++guard > 2000000) break;   // hang-avoidance only
        }
      }
      __syncthreads();
      __threadfence();
    }
    ((float4*)hlds)[tid] = ((const float4*)(hb + par * 2048))[tid];  // 8KB h_prev
    __syncthreads();
    // GEMV: acc[b] over k chunk of 64
    float a0=0,a1=0,a2=0,a3=0,a4=0,a5=0,a6=0,a7=0;
    {
      const float* wr = wlds + r * 257 + kc * 64;
      const float4* h4 = (const float4*)hlds + kc * 128;
      #pragma unroll 8
      for (int kk = 0; kk < 64; ++kk) {
        float w = wr[kk];
        float4 h0 = h4[kk * 2];
        float4 h1 = h4[kk * 2 + 1];
        a0 += w * h0.x; a1 += w * h0.y; a2 += w * h0.z; a3 += w * h0.w;
        a4 += w * h1.x; a5 += w * h1.y; a6 += w * h1.z; a7 += w * h1.w;
      }
    }
    {
      float2* pp = (float2*)(part + (kc * 128 + r) * 10);
      pp[0] = make_float2(a0, a1); pp[1] = make_float2(a2, a3);
      pp[2] = make_float2(a4, a5); pp[3] = make_float2(a6, a7);
    }
    __syncthreads();
    if (tid < 256) {
      const int mrow = t * 32 + bg * 8 + ub;
      const u16* gp = G + (size_t)mrow * 2048 + dir * 1024 + slice * 32 + ujj;
      float si = bf2f(gp[0]);
      float sf = bf2f(gp[256]);
      float sg = bf2f(gp[512]);
      float so = bf2f(gp[768]);
      const int rb = ujj * 4;
      #pragma unroll
      for (int c = 0; c < 4; ++c) {
        const float* pb = part + (c * 128 + rb) * 10 + ub;
        si += pb[0]; sf += pb[10]; sg += pb[20]; so += pb[30];
      }
      float cold = clds[ujj * 8 + ub];
      float ig = sigf(si), fg = sigf(sf), gv = tanh_f(sg), og = sigf(so);
      float cn = fg * cold + ig * gv;
      float hn = og * tanh_f(cn);
      clds[ujj * 8 + ub] = cn;
      hb[(par ^ 1) * 2048 + (slice * 32 + ujj) * 8 + ub] = hn;
      const size_t oidx = ((size_t)t * 32 + (bg * 8 + ub)) * 512 + dir * 256 + slice * 32 + ujj;
      if (Xbf) Xbf[oidx] = f2bf(hn);
      else     Xf[oidx] = hn;
    }
    __threadfence();
    __syncthreads();
    if (tid == 0) {
      __hip_atomic_fetch_add(mycnt, 1, __ATOMIC_RELEASE, __HIP_MEMORY_SCOPE_AGENT);
    }
  }
}

// ---------------- LayerNorm + classifier head; logits -> d_out+1 ----------------
__global__ void head_k(const float* __restrict__ X2, const float* __restrict__ gamma,
                       const float* __restrict__ beta, const float* __restrict__ cw,
                       const float* __restrict__ cb, float* __restrict__ out) {
  __shared__ float red[9][64];
  const int m = blockIdx.x, lane = threadIdx.x;
  const int s = m >> 5, b = m & 31;
  const float4* xp = (const float4*)(X2 + (size_t)m * 512) + lane * 2;
  float4 x0 = xp[0], x1 = xp[1];
  float sm = x0.x + x0.y + x0.z + x0.w + x1.x + x1.y + x1.z + x1.w;
  float sq = x0.x*x0.x + x0.y*x0.y + x0.z*x0.z + x0.w*x0.w
           + x1.x*x1.x + x1.y*x1.y + x1.z*x1.z + x1.w*x1.w;
  #pragma unroll
  for (int off = 32; off > 0; off >>= 1) {
    sm += __shfl_xor(sm, off, 64);
    sq += __shfl_xor(sq, off, 64);
  }
  const float mu = sm * (1.0f / 512.0f);
  const float var = sq * (1.0f / 512.0f) - mu * mu;
  const float rs = rsqrtf(var + 1e-5f);
  const float4* gp = (const float4*)gamma + lane * 2;
  const float4* bp = (const float4*)beta + lane * 2;
  float4 g0 = gp[0], g1 = gp[1], be0 = bp[0], be1 = bp[1];
  float nv[8];
  nv[0] = (x0.x - mu) * rs * g0.x + be0.x;
  nv[1] = (x0.y - mu) * rs * g0.y + be0.y;
  nv[2] = (x0.z - mu) * rs * g0.z + be0.z;
  nv[3] = (x0.w - mu) * rs * g0.w + be0.w;
  nv[4] = (x1.x - mu) * rs * g1.x + be1.x;
  nv[5] = (x1.y - mu) * rs * g1.y + be1.y;
  nv[6] = (x1.z - mu) * rs * g1.z + be1.z;
  nv[7] = (x1.w - mu) * rs * g1.w + be1.w;
  #pragma unroll
  for (int c = 0; c < 9; ++c) {
    const float4* wp = (const float4*)(cw + (size_t)c * 512) + lane * 2;
    float4 w0 = wp[0], w1 = wp[1];
    red[c][lane] = nv[0]*w0.x + nv[1]*w0.y + nv[2]*w0.z + nv[3]*w0.w
                 + nv[4]*w1.x + nv[5]*w1.y + nv[6]*w1.z + nv[7]*w1.w;
  }
  __syncthreads();
  if (lane < 9) {
    float t = 0.f;
    for (int i = 0; i < 64; ++i) t += red[lane][i];
    out[1 + ((size_t)b * 512 + s) * 9 + lane] = t + cb[lane];
  }
}

// ---------------- CRF NLL: one wave per batch element ----------------
__global__ void crf_k(const float* __restrict__ logits, const int* __restrict__ labels,
                      const int* __restrict__ lens, const float* __restrict__ tr,
                      float* __restrict__ loss) {
  const int b = blockIdx.x, lane = threadIdx.x;
  const int len = lens[b];
  float trj[9];
  #pragma unroll
  for (int i = 0; i < 9; ++i) trj[i] = 0.f;
  if (lane < 9) {
    #pragma unroll
    for (int i = 0; i < 9; ++i) trj[i] = tr[i * 11 + lane];
  }
  float alpha = -1e30f;
  if (lane < 9) alpha = tr[9 * 11 + lane] + logits[(size_t)b * 512 * 9 + lane];
  for (int t = 1; t < len; ++t) {
    float e = (lane < 9) ? logits[((size_t)b * 512 + t) * 9 + lane] : 0.f;
    float v[9];
    float mx = -1e30f;
    #pragma unroll
    for (int i = 0; i < 9; ++i) {
      v[i] = __shfl(alpha, i, 64) + trj[i];
      mx = fmaxf(mx, v[i]);
    }
    float ss = 0.f;
    #pragma unroll
    for (int i = 0; i < 9; ++i) ss += __expf(v[i] - mx);
    float na = mx + __logf(ss) + e;
    if (lane < 9) alpha = na;
  }
  float fin = (lane < 9) ? alpha + tr[lane * 11 + 10] : -1e30f;
  float mx = fin;
  #pragma unroll
  for (int off = 8; off > 0; off >>= 1) mx = fmaxf(mx, __shfl_xor(mx, off, 64));
  float es = (lane < 9) ? __expf(fin - mx) : 0.f;
  #pragma unroll
  for (int off = 8; off > 0; off >>= 1) es += __shfl_xor(es, off, 64);
  const float logZ = mx + __logf(es);
  float emit = 0.f, ts = 0.f;
  for (int t = lane; t < len; t += 64) {
    int y = labels[b * 512 + t];
    emit += logits[((size_t)b * 512 + t) * 9 + y];
  }
  for (int t = 1 + lane; t < len; t += 64) {
    int y0 = labels[b * 512 + t - 1], y1 = labels[b * 512 + t];
    ts += tr[y0 * 11 + y1];
  }
  #pragma unroll
  for (int off = 32; off > 0; off >>= 1) {
    emit += __shfl_xor(emit, off, 64);
    ts += __shfl_xor(ts, off, 64);
  }
  if (lane == 0) {
    int y0 = labels[b * 512], yl = labels[b * 512 + len - 1];
    float gold = emit + ts + tr[9 * 11 + y0] + tr[yl * 11 + 10];
    atomicAdd(loss, (logZ - gold) * (1.0f / 32.0f));
  }
}

extern "C" void kernel_launch(void* const* d_in, const int* in_sizes, int n_in,
                              void* d_out, int out_size, void* d_ws, size_t ws_size,
                              hipStream_t stream) {
  const int* ids = (const int*)d_in[0];
  const int* amask = (const int*)d_in[1];
  const int* lens = (const int*)d_in[2];
  const int* labels = (const int*)d_in[3];
  const float* emb = (const float*)d_in[4];
  const float* w_ih = (const float*)d_in[5];
  const float* w_hh = (const float*)d_in[6];
  const float* b_ih = (const float*)d_in[7];
  const float* b_hh = (const float*)d_in[8];
  const float* gamma = (const float*)d_in[9];
  const float* beta = (const float*)d_in[10];
  const float* cw = (const float*)d_in[11];
  const float* cb = (const float*)d_in[12];
  const float* tr = (const float*)d_in[13];
  (void)in_sizes; (void)n_in; (void)out_size;

  if (ws_size < WS_NEEDED) return;  // workspace too small -> clean failure

  char* p = (char*)d_ws;
  u16* X0 = (u16*)p;      p += (size_t)16384 * 512 * 2;       // 16.78 MB
  u16* Wbf = (u16*)p;     p += (size_t)2 * 2 * 1024 * 512 * 2; // 4.19 MB
  u16* G = (u16*)p;       p += (size_t)16384 * 2048 * 2;       // 67.1 MB
  u16* X1 = (u16*)p;      p += (size_t)16384 * 512 * 2;        // 16.78 MB
  float* X2 = (float*)p;  p += (size_t)16384 * 512 * 4;        // 33.55 MB
  float* Hb = (float*)p;  p += (size_t)32768 * 4;              // 128 KB
  int* cnt = (int*)p;     p += 256;
  float* out = (float*)d_out;

  hipFuncSetAttribute((const void*)rec_k, hipFuncAttributeMaxDynamicSharedMemorySize,
                      REC_SMEM_BYTES);

  prep_k<<<16384, 64, 0, stream>>>(ids, amask, emb, X0);
  conv_k<<<1024, 256, 0, stream>>>(w_ih, Wbf, 262144);
  zero_k<<<128, 256, 0, stream>>>(Hb, cnt, out);
  // Layer 0
  gemm_k<<<dim3(256, 32), 256, 0, stream>>>(X0, Wbf, b_ih, b_hh, G);
  rec_k<<<64, 512, REC_SMEM_BYTES, stream>>>(G, w_hh, Hb, cnt, X1, nullptr);
  zero_k<<<128, 256, 0, stream>>>(Hb, cnt, out);
  // Layer 1
  gemm_k<<<dim3(256, 32), 256, 0, stream>>>(X1, Wbf + 2 * 1024 * 512,
                                            b_ih + 2048, b_hh + 2048, G);
  rec_k<<<64, 512, REC_SMEM_BYTES, stream>>>(G, w_hh + 2 * 1024 * 256, Hb, cnt,
                                             nullptr, X2);
  // Head + CRF
  head_k<<<16384, 64, 0, stream>>>(X2, gamma, beta, cw, cb, out);
  crf_k<<<32, 64, 0, stream>>>(out + 1, labels, lens, tr, out);
}

// Round 2
// 9453.498 us; speedup vs baseline: 2.5246x; 2.5246x over previous
//
#include <hip/hip_runtime.h>

// Problem dims
#define B_ 32
#define S_ 512
#define D_ 512
#define H_ 256

typedef float floatx4 __attribute__((ext_vector_type(4)));
typedef short short8v __attribute__((ext_vector_type(8)));
typedef unsigned short u16;
typedef unsigned int u32;
typedef unsigned long long u64;

// LDS: wlds 128*257 + hlds 2048 + part2 4*8*132 + clds 256  (floats)
#define REC_SMEM_DW (128*257 + 2048 + 4*8*132 + 256)
#define REC_SMEM_BYTES (REC_SMEM_DW * 4)   // 157696 B < 160 KiB
#define WS_NEEDED 138543360ull

__device__ __forceinline__ u16 f2bf(float f) {
  u32 x = __float_as_uint(f);
  x += 0x7fffu + ((x >> 16) & 1u);   // RNE
  return (u16)(x >> 16);
}
__device__ __forceinline__ float bf2f(u16 h) {
  return __uint_as_float(((u32)h) << 16);
}
__device__ __forceinline__ float sigf(float x) {
  return 1.0f / (1.0f + __expf(-x));
}
__device__ __forceinline__ float tanh_f(float x) {
  float e = __expf(-2.0f * fabsf(x));
  float r = (1.0f - e) / (1.0f + e);
  return copysignf(r, x);
}

struct alignas(16) U16x8 { u16 v[8]; };

// ---------------- embedding -> X0 bf16, time-major (m = s*32+b, 512 feats) ----------------
__global__ void prep_k(const int* __restrict__ ids, const int* __restrict__ amask,
                       const float* __restrict__ emb, u16* __restrict__ X0) {
  int m = blockIdx.x;            // m = s*32 + b
  int lane = threadIdx.x;        // 64
  int s = m >> 5, b = m & 31;
  int id = ids[b * S_ + s];
  int mk = amask[b * S_ + s];
  const float4* src = (const float4*)(emb + (size_t)id * D_) + lane * 2;
  float4 v0 = src[0], v1 = src[1];
  if (!mk) { v0 = make_float4(0,0,0,0); v1 = make_float4(0,0,0,0); }
  U16x8 o;
  o.v[0]=f2bf(v0.x); o.v[1]=f2bf(v0.y); o.v[2]=f2bf(v0.z); o.v[3]=f2bf(v0.w);
  o.v[4]=f2bf(v1.x); o.v[5]=f2bf(v1.y); o.v[6]=f2bf(v1.z); o.v[7]=f2bf(v1.w);
  *(U16x8*)(X0 + (size_t)m * D_ + lane * 8) = o;
}

// ---------------- fp32 -> bf16 weight convert (w_ih, 2*2*1024*512 elems) ----------------
__global__ void conv_k(const float* __restrict__ w, u16* __restrict__ wbf, int n8) {
  int idx = blockIdx.x * blockDim.x + threadIdx.x;
  if (idx >= n8) return;
  const float4* s = (const float4*)w + (size_t)idx * 2;
  float4 v0 = s[0], v1 = s[1];
  U16x8 o;
  o.v[0]=f2bf(v0.x); o.v[1]=f2bf(v0.y); o.v[2]=f2bf(v0.z); o.v[3]=f2bf(v0.w);
  o.v[4]=f2bf(v1.x); o.v[5]=f2bf(v1.y); o.v[6]=f2bf(v1.z); o.v[7]=f2bf(v1.w);
  *(U16x8*)(wbf + (size_t)idx * 8) = o;
}

// ---------------- zero Hbuf / sync counters / loss ----------------
__global__ void zero_k(float* __restrict__ Hb, int* __restrict__ cnt, float* __restrict__ loss) {
  int idx = blockIdx.x * 256 + threadIdx.x;   // grid 128x256 = 32768
  if (idx < 32768) Hb[idx] = 0.f;
  if (idx < 8) cnt[idx] = 0;
  if (idx == 0) *loss = 0.f;
}

// ---------------- bf16 MFMA GEMM: G[m][n] = A[m][:] . W[n][:] + bih[n] + bhh[n] ----------------
__global__ void gemm_k(const u16* __restrict__ A, const u16* __restrict__ W,
                       const float* __restrict__ bih, const float* __restrict__ bhh,
                       u16* __restrict__ G) {
  __shared__ short Asm[64 * 40];
  __shared__ short Bsm[64 * 40];
  const int tid = threadIdx.x;
  const int m0 = blockIdx.x * 64, n0 = blockIdx.y * 64;
  const int wid = tid >> 6, lane = tid & 63;
  const int quad = lane >> 4, lr = lane & 15;
  const int wm = (wid >> 1) * 32, wn = (wid & 1) * 32;
  const int lrow = tid >> 2, lk = (tid & 3) * 8;
  floatx4 acc00 = {0,0,0,0}, acc01 = {0,0,0,0}, acc10 = {0,0,0,0}, acc11 = {0,0,0,0};
  for (int kt = 0; kt < 16; ++kt) {
    const int k0 = kt * 32;
    uint4 av = *(const uint4*)(A + (size_t)(m0 + lrow) * 512 + k0 + lk);
    uint4 bv = *(const uint4*)(W + (size_t)(n0 + lrow) * 512 + k0 + lk);
    __syncthreads();
    *(uint4*)&Asm[lrow * 40 + lk] = av;
    *(uint4*)&Bsm[lrow * 40 + lk] = bv;
    __syncthreads();
    short8v a0 = *(const short8v*)&Asm[(wm + lr) * 40 + quad * 8];
    short8v a1 = *(const short8v*)&Asm[(wm + 16 + lr) * 40 + quad * 8];
    short8v b0 = *(const short8v*)&Bsm[(wn + lr) * 40 + quad * 8];
    short8v b1 = *(const short8v*)&Bsm[(wn + 16 + lr) * 40 + quad * 8];
    acc00 = __builtin_amdgcn_mfma_f32_16x16x32_bf16(a0, b0, acc00, 0, 0, 0);
    acc01 = __builtin_amdgcn_mfma_f32_16x16x32_bf16(a0, b1, acc01, 0, 0, 0);
    acc10 = __builtin_amdgcn_mfma_f32_16x16x32_bf16(a1, b0, acc10, 0, 0, 0);
    acc11 = __builtin_amdgcn_mfma_f32_16x16x32_bf16(a1, b1, acc11, 0, 0, 0);
  }
  #pragma unroll
  for (int j = 0; j < 2; ++j) {
    const int n = n0 + wn + j * 16 + lr;
    const float bias = bih[n] + bhh[n];
    #pragma unroll
    for (int i = 0; i < 2; ++i) {
      const int mb = m0 + wm + i * 16 + quad * 4;
      floatx4 av = (i == 0) ? (j == 0 ? acc00 : acc01) : (j == 0 ? acc10 : acc11);
      #pragma unroll
      for (int rr = 0; rr < 4; ++rr) {
        G[(size_t)(mb + rr) * 2048 + n] = f2bf(av[rr] + bias);
      }
    }
  }
}

// ---------------- LSTM recurrence, one layer, both dirs ----------------
// grid: 64 blocks = dir(2) x slice(8) x bg(4); 512 threads; Whh slice in LDS (fp32).
// Cross-wg h exchange: relaxed agent-scope atomics (sc1, NO bulk L2 wb/inv) +
// explicit per-wave s_waitcnt vmcnt(0) before the counter bump. 2 barriers/step.
__launch_bounds__(512, 1)
__global__ void rec_k(const u16* __restrict__ G, const float* __restrict__ whh_l,
                      float* __restrict__ Hbuf, int* __restrict__ cnt,
                      u16* __restrict__ Xbf, float* __restrict__ Xf) {
  extern __shared__ float smem[];
  float* wlds = smem;                          // [128][257]
  float* hlds = smem + 128 * 257;              // [256][8]
  float* part2 = hlds + 2048;                  // [4][8][132]
  float* clds = part2 + 4 * 8 * 132;           // [32][8]
  u64* hlds64 = (u64*)hlds;
  const int tid = threadIdx.x;
  const int dir = blockIdx.x >> 5;
  const int slice = (blockIdx.x >> 2) & 7;
  const int bg = blockIdx.x & 3;
  const float* whh = whh_l + dir * (1024 * 256);
  // Load weight slice: local row r = jj*4 + type  <->  global row = type*256 + slice*32 + jj
  for (int idx = tid; idx < 128 * 256; idx += 512) {
    int r = idx >> 8, k = idx & 255;
    int grow = (r & 3) * 256 + slice * 32 + (r >> 2);
    wlds[r * 257 + k] = whh[grow * 256 + k];
  }
  if (tid < 256) clds[tid] = 0.f;
  int* mycnt = cnt + dir * 4 + bg;
  float* hbgrp = Hbuf + (dir * 4 + bg) * 4096;
  const int kc = tid >> 7;        // k-chunk 0..3
  const int r = tid & 127;        // local gate row
  const int ub = tid >> 5;        // updater: batch in group (tid<256)
  const int ujj = tid & 31;       // updater: hidden within slice
  __syncthreads();
  for (int q = 0; q < 512; ++q) {
    const int t = dir ? (511 - q) : q;
    const int par = q & 1;
    if (q > 0) {
      const int target = 32 * q;
      int spin = 0;
      while (__hip_atomic_load(mycnt, __ATOMIC_RELAXED, __HIP_MEMORY_SCOPE_AGENT) < target) {
        if (++spin > (1 << 18)) break;   // hang-avoidance only
      }
    }
    // G prefetch (raw bf16 bits; convert after B2 so the vmcnt wait lands at B1)
    u16 gv0 = 0, gv1 = 0, gv2 = 0, gv3 = 0;
    if (tid < 256) {
      const int mrow = t * 32 + bg * 8 + ub;
      const u16* gp = G + (size_t)mrow * 2048 + dir * 1024 + slice * 32 + ujj;
      gv0 = gp[0]; gv1 = gp[256]; gv2 = gp[512]; gv3 = gp[768];
    }
    // h_prev: coherent (sc1) loads from the group's double buffer -> LDS
    {
      const u64* src = (const u64*)(hbgrp + par * 2048);
      u64 h0 = __hip_atomic_load(src + tid, __ATOMIC_RELAXED, __HIP_MEMORY_SCOPE_AGENT);
      u64 h1 = __hip_atomic_load(src + 512 + tid, __ATOMIC_RELAXED, __HIP_MEMORY_SCOPE_AGENT);
      hlds64[tid] = h0;
      hlds64[512 + tid] = h1;
    }
    __syncthreads();   // B1
    // GEMV over k-chunk of 64
    float a0=0,a1=0,a2=0,a3=0,a4=0,a5=0,a6=0,a7=0;
    {
      const float* wr = wlds + r * 257 + kc * 64;
      const float4* h4 = (const float4*)hlds + kc * 128;
      #pragma unroll 8
      for (int kk = 0; kk < 64; ++kk) {
        float w = wr[kk];
        float4 h0 = h4[kk * 2];
        float4 h1 = h4[kk * 2 + 1];
        a0 += w * h0.x; a1 += w * h0.y; a2 += w * h0.z; a3 += w * h0.w;
        a4 += w * h1.x; a5 += w * h1.y; a6 += w * h1.z; a7 += w * h1.w;
      }
    }
    {
      float* pb = part2 + (kc * 8) * 132 + r;
      pb[0*132]=a0; pb[1*132]=a1; pb[2*132]=a2; pb[3*132]=a3;
      pb[4*132]=a4; pb[5*132]=a5; pb[6*132]=a6; pb[7*132]=a7;
    }
    __syncthreads();   // B2
    if (tid < 256) {
      float si = bf2f(gv0), sf = bf2f(gv1), sg = bf2f(gv2), so = bf2f(gv3);
      #pragma unroll
      for (int c = 0; c < 4; ++c) {
        float4 pc = *(const float4*)&part2[(c * 8 + ub) * 132 + ujj * 4];
        si += pc.x; sf += pc.y; sg += pc.z; so += pc.w;
      }
      float cold = clds[ujj * 8 + ub];
      float ig = sigf(si), fg = sigf(sf), gv = tanh_f(sg), og = sigf(so);
      float cn = fg * cold + ig * gv;
      float hn = og * tanh_f(cn);
      clds[ujj * 8 + ub] = cn;
      __hip_atomic_store(hbgrp + (par ^ 1) * 2048 + (slice * 32 + ujj) * 8 + ub, hn,
                         __ATOMIC_RELAXED, __HIP_MEMORY_SCOPE_AGENT);
      const size_t oidx = ((size_t)t * 32 + (bg * 8 + ub)) * 512 + dir * 256 + slice * 32 + ujj;
      if (Xbf) Xbf[oidx] = f2bf(hn);
      else     Xf[oidx] = hn;
      asm volatile("s_waitcnt vmcnt(0)" ::: "memory");   // per-wave: h stores done
      if ((tid & 63) == 0) {
        __hip_atomic_fetch_add(mycnt, 1, __ATOMIC_RELAXED, __HIP_MEMORY_SCOPE_AGENT);
      }
    }
    // no end-of-step barrier: next step's counter poll orders everything;
    // hlds rewrite is safe (updaters read only part2/clds/G after B2).
  }
}

// ---------------- LayerNorm + classifier head; logits -> d_out+1 ----------------
__global__ void head_k(const float* __restrict__ X2, const float* __restrict__ gamma,
                       const float* __restrict__ beta, const float* __restrict__ cw,
                       const float* __restrict__ cb, float* __restrict__ out) {
  __shared__ float red[9][64];
  const int m = blockIdx.x, lane = threadIdx.x;
  const int s = m >> 5, b = m & 31;
  const float4* xp = (const float4*)(X2 + (size_t)m * 512) + lane * 2;
  float4 x0 = xp[0], x1 = xp[1];
  float sm = x0.x + x0.y + x0.z + x0.w + x1.x + x1.y + x1.z + x1.w;
  float sq = x0.x*x0.x + x0.y*x0.y + x0.z*x0.z + x0.w*x0.w
           + x1.x*x1.x + x1.y*x1.y + x1.z*x1.z + x1.w*x1.w;
  #pragma unroll
  for (int off = 32; off > 0; off >>= 1) {
    sm += __shfl_xor(sm, off, 64);
    sq += __shfl_xor(sq, off, 64);
  }
  const float mu = sm * (1.0f / 512.0f);
  const float var = sq * (1.0f / 512.0f) - mu * mu;
  const float rs = rsqrtf(var + 1e-5f);
  const float4* gp = (const float4*)gamma + lane * 2;
  const float4* bp = (const float4*)beta + lane * 2;
  float4 g0 = gp[0], g1 = gp[1], be0 = bp[0], be1 = bp[1];
  float nv[8];
  nv[0] = (x0.x - mu) * rs * g0.x + be0.x;
  nv[1] = (x0.y - mu) * rs * g0.y + be0.y;
  nv[2] = (x0.z - mu) * rs * g0.z + be0.z;
  nv[3] = (x0.w - mu) * rs * g0.w + be0.w;
  nv[4] = (x1.x - mu) * rs * g1.x + be1.x;
  nv[5] = (x1.y - mu) * rs * g1.y + be1.y;
  nv[6] = (x1.z - mu) * rs * g1.z + be1.z;
  nv[7] = (x1.w - mu) * rs * g1.w + be1.w;
  #pragma unroll
  for (int c = 0; c < 9; ++c) {
    const float4* wp = (const float4*)(cw + (size_t)c * 512) + lane * 2;
    float4 w0 = wp[0], w1 = wp[1];
    red[c][lane] = nv[0]*w0.x + nv[1]*w0.y + nv[2]*w0.z + nv[3]*w0.w
                 + nv[4]*w1.x + nv[5]*w1.y + nv[6]*w1.z + nv[7]*w1.w;
  }
  __syncthreads();
  if (lane < 9) {
    float t = 0.f;
    for (int i = 0; i < 64; ++i) t += red[lane][i];
    out[1 + ((size_t)b * 512 + s) * 9 + lane] = t + cb[lane];
  }
}

// ---------------- CRF NLL: one wave per batch element ----------------
__global__ void crf_k(const float* __restrict__ logits, const int* __restrict__ labels,
                      const int* __restrict__ lens, const float* __restrict__ tr,
                      float* __restrict__ loss) {
  const int b = blockIdx.x, lane = threadIdx.x;
  const int len = lens[b];
  float trj[9];
  #pragma unroll
  for (int i = 0; i < 9; ++i) trj[i] = 0.f;
  if (lane < 9) {
    #pragma unroll
    for (int i = 0; i < 9; ++i) trj[i] = tr[i * 11 + lane];
  }
  float alpha = -1e30f;
  if (lane < 9) alpha = tr[9 * 11 + lane] + logits[(size_t)b * 512 * 9 + lane];
  for (int t = 1; t < len; ++t) {
    float e = (lane < 9) ? logits[((size_t)b * 512 + t) * 9 + lane] : 0.f;
    float v[9];
    float mx = -1e30f;
    #pragma unroll
    for (int i = 0; i < 9; ++i) {
      v[i] = __shfl(alpha, i, 64) + trj[i];
      mx = fmaxf(mx, v[i]);
    }
    float ss = 0.f;
    #pragma unroll
    for (int i = 0; i < 9; ++i) ss += __expf(v[i] - mx);
    float na = mx + __logf(ss) + e;
    if (lane < 9) alpha = na;
  }
  float fin = (lane < 9) ? alpha + tr[lane * 11 + 10] : -1e30f;
  float mx = fin;
  #pragma unroll
  for (int off = 8; off > 0; off >>= 1) mx = fmaxf(mx, __shfl_xor(mx, off, 64));
  float es = (lane < 9) ? __expf(fin - mx) : 0.f;
  #pragma unroll
  for (int off = 8; off > 0; off >>= 1) es += __shfl_xor(es, off, 64);
  const float logZ = mx + __logf(es);
  float emit = 0.f, ts = 0.f;
  for (int t = lane; t < len; t += 64) {
    int y = labels[b * 512 + t];
    emit += logits[((size_t)b * 512 + t) * 9 + y];
  }
  for (int t = 1 + lane; t < len; t += 64) {
    int y0 = labels[b * 512 + t - 1], y1 = labels[b * 512 + t];
    ts += tr[y0 * 11 + y1];
  }
  #pragma unroll
  for (int off = 32; off > 0; off >>= 1) {
    emit += __shfl_xor(emit, off, 64);
    ts += __shfl_xor(ts, off, 64);
  }
  if (lane == 0) {
    int y0 = labels[b * 512], yl = labels[b * 512 + len - 1];
    float gold = emit + ts + tr[9 * 11 + y0] + tr[yl * 11 + 10];
    atomicAdd(loss, (logZ - gold) * (1.0f / 32.0f));
  }
}

extern "C" void kernel_launch(void* const* d_in, const int* in_sizes, int n_in,
                              void* d_out, int out_size, void* d_ws, size_t ws_size,
                              hipStream_t stream) {
  const int* ids = (const int*)d_in[0];
  const int* amask = (const int*)d_in[1];
  const int* lens = (const int*)d_in[2];
  const int* labels = (const int*)d_in[3];
  const float* emb = (const float*)d_in[4];
  const float* w_ih = (const float*)d_in[5];
  const float* w_hh = (const float*)d_in[6];
  const float* b_ih = (const float*)d_in[7];
  const float* b_hh = (const float*)d_in[8];
  const float* gamma = (const float*)d_in[9];
  const float* beta = (const float*)d_in[10];
  const float* cw = (const float*)d_in[11];
  const float* cb = (const float*)d_in[12];
  const float* tr = (const float*)d_in[13];
  (void)in_sizes; (void)n_in; (void)out_size;

  if (ws_size < WS_NEEDED) return;  // workspace too small -> clean failure

  char* p = (char*)d_ws;
  u16* X0 = (u16*)p;      p += (size_t)16384 * 512 * 2;       // 16.78 MB
  u16* Wbf = (u16*)p;     p += (size_t)2 * 2 * 1024 * 512 * 2; // 4.19 MB
  u16* G = (u16*)p;       p += (size_t)16384 * 2048 * 2;       // 67.1 MB
  u16* X1 = (u16*)p;      p += (size_t)16384 * 512 * 2;        // 16.78 MB
  float* X2 = (float*)p;  p += (size_t)16384 * 512 * 4;        // 33.55 MB
  float* Hb = (float*)p;  p += (size_t)32768 * 4;              // 128 KB
  int* cnt = (int*)p;     p += 256;
  float* out = (float*)d_out;

  hipFuncSetAttribute((const void*)rec_k, hipFuncAttributeMaxDynamicSharedMemorySize,
                      REC_SMEM_BYTES);

  prep_k<<<16384, 64, 0, stream>>>(ids, amask, emb, X0);
  conv_k<<<1024, 256, 0, stream>>>(w_ih, Wbf, 262144);
  zero_k<<<128, 256, 0, stream>>>(Hb, cnt, out);
  // Layer 0
  gemm_k<<<dim3(256, 32), 256, 0, stream>>>(X0, Wbf, b_ih, b_hh, G);
  rec_k<<<64, 512, REC_SMEM_BYTES, stream>>>(G, w_hh, Hb, cnt, X1, nullptr);
  zero_k<<<128, 256, 0, stream>>>(Hb, cnt, out);
  // Layer 1
  gemm_k<<<dim3(256, 32), 256, 0, stream>>>(X1, Wbf + 2 * 1024 * 512,
                                            b_ih + 2048, b_hh + 2048, G);
  rec_k<<<64, 512, REC_SMEM_BYTES, stream>>>(G, w_hh + 2 * 1024 * 256, Hb, cnt,
                                             nullptr, X2);
  // Head + CRF
  head_k<<<16384, 64, 0, stream>>>(X2, gamma, beta, cw, cb, out);
  crf_k<<<32, 64, 0, stream>>>(out + 1, labels, lens, tr, out);
}

// Round 3
// 3988.098 us; speedup vs baseline: 5.9845x; 2.3704x over previous
//
#include <hip/hip_runtime.h>

// Problem dims
#define B_ 32
#define S_ 512
#define D_ 512
#define H_ 256

typedef float floatx4 __attribute__((ext_vector_type(4)));
typedef short short8v __attribute__((ext_vector_type(8)));
typedef unsigned short u16;
typedef unsigned int u32;
typedef unsigned long long u64;

#define WS_NEEDED 138543616ull

__device__ __forceinline__ u16 f2bf(float f) {
  u32 x = __float_as_uint(f);
  x += 0x7fffu + ((x >> 16) & 1u);   // RNE
  return (u16)(x >> 16);
}
__device__ __forceinline__ float bf2f(u16 h) {
  return __uint_as_float(((u32)h) << 16);
}
__device__ __forceinline__ float sigf(float x) {
  return 1.0f / (1.0f + __expf(-x));
}
__device__ __forceinline__ float tanh_f(float x) {
  float e = __expf(-2.0f * fabsf(x));
  float r = (1.0f - e) / (1.0f + e);
  return copysignf(r, x);
}

struct alignas(16) U16x8 { u16 v[8]; };

// ---------------- embedding -> X0 bf16, time-major (m = s*32+b, 512 feats) ----------------
__global__ void prep_k(const int* __restrict__ ids, const int* __restrict__ amask,
                       const float* __restrict__ emb, u16* __restrict__ X0) {
  int m = blockIdx.x;            // m = s*32 + b
  int lane = threadIdx.x;        // 64
  int s = m >> 5, b = m & 31;
  int id = ids[b * S_ + s];
  int mk = amask[b * S_ + s];
  const float4* src = (const float4*)(emb + (size_t)id * D_) + lane * 2;
  float4 v0 = src[0], v1 = src[1];
  if (!mk) { v0 = make_float4(0,0,0,0); v1 = make_float4(0,0,0,0); }
  U16x8 o;
  o.v[0]=f2bf(v0.x); o.v[1]=f2bf(v0.y); o.v[2]=f2bf(v0.z); o.v[3]=f2bf(v0.w);
  o.v[4]=f2bf(v1.x); o.v[5]=f2bf(v1.y); o.v[6]=f2bf(v1.z); o.v[7]=f2bf(v1.w);
  *(U16x8*)(X0 + (size_t)m * D_ + lane * 8) = o;
}

// ---------------- fp32 -> bf16 weight convert (w_ih, 2*2*1024*512 elems) ----------------
__global__ void conv_k(const float* __restrict__ w, u16* __restrict__ wbf, int n8) {
  int idx = blockIdx.x * blockDim.x + threadIdx.x;
  if (idx >= n8) return;
  const float4* s = (const float4*)w + (size_t)idx * 2;
  float4 v0 = s[0], v1 = s[1];
  U16x8 o;
  o.v[0]=f2bf(v0.x); o.v[1]=f2bf(v0.y); o.v[2]=f2bf(v0.z); o.v[3]=f2bf(v0.w);
  o.v[4]=f2bf(v1.x); o.v[5]=f2bf(v1.y); o.v[6]=f2bf(v1.z); o.v[7]=f2bf(v1.w);
  *(U16x8*)(wbf + (size_t)idx * 8) = o;
}

// ---------------- zero sync counters / loss ----------------
__global__ void zero_k(int* __restrict__ cnt, float* __restrict__ loss) {
  int idx = threadIdx.x;
  if (idx < 8) cnt[idx * 16] = 0;    // counters padded 64B apart
  if (idx == 0) *loss = 0.f;
}

// ---------------- bf16 MFMA GEMM: G[m][n] = A[m][:] . W[n][:] + bih[n] + bhh[n] ----------------
__global__ void gemm_k(const u16* __restrict__ A, const u16* __restrict__ W,
                       const float* __restrict__ bih, const float* __restrict__ bhh,
                       u16* __restrict__ G) {
  __shared__ short Asm[64 * 40];
  __shared__ short Bsm[64 * 40];
  const int tid = threadIdx.x;
  const int m0 = blockIdx.x * 64, n0 = blockIdx.y * 64;
  const int wid = tid >> 6, lane = tid & 63;
  const int quad = lane >> 4, lr = lane & 15;
  const int wm = (wid >> 1) * 32, wn = (wid & 1) * 32;
  const int lrow = tid >> 2, lk = (tid & 3) * 8;
  floatx4 acc00 = {0,0,0,0}, acc01 = {0,0,0,0}, acc10 = {0,0,0,0}, acc11 = {0,0,0,0};
  for (int kt = 0; kt < 16; ++kt) {
    const int k0 = kt * 32;
    uint4 av = *(const uint4*)(A + (size_t)(m0 + lrow) * 512 + k0 + lk);
    uint4 bv = *(const uint4*)(W + (size_t)(n0 + lrow) * 512 + k0 + lk);
    __syncthreads();
    *(uint4*)&Asm[lrow * 40 + lk] = av;
    *(uint4*)&Bsm[lrow * 40 + lk] = bv;
    __syncthreads();
    short8v a0 = *(const short8v*)&Asm[(wm + lr) * 40 + quad * 8];
    short8v a1 = *(const short8v*)&Asm[(wm + 16 + lr) * 40 + quad * 8];
    short8v b0 = *(const short8v*)&Bsm[(wn + lr) * 40 + quad * 8];
    short8v b1 = *(const short8v*)&Bsm[(wn + 16 + lr) * 40 + quad * 8];
    acc00 = __builtin_amdgcn_mfma_f32_16x16x32_bf16(a0, b0, acc00, 0, 0, 0);
    acc01 = __builtin_amdgcn_mfma_f32_16x16x32_bf16(a0, b1, acc01, 0, 0, 0);
    acc10 = __builtin_amdgcn_mfma_f32_16x16x32_bf16(a1, b0, acc10, 0, 0, 0);
    acc11 = __builtin_amdgcn_mfma_f32_16x16x32_bf16(a1, b1, acc11, 0, 0, 0);
  }
  #pragma unroll
  for (int j = 0; j < 2; ++j) {
    const int n = n0 + wn + j * 16 + lr;
    const float bias = bih[n] + bhh[n];
    #pragma unroll
    for (int i = 0; i < 2; ++i) {
      const int mb = m0 + wm + i * 16 + quad * 4;
      floatx4 av = (i == 0) ? (j == 0 ? acc00 : acc01) : (j == 0 ? acc10 : acc11);
      #pragma unroll
      for (int rr = 0; rr < 4; ++rr) {
        G[(size_t)(mb + rr) * 2048 + n] = f2bf(av[rr] + bias);
      }
    }
  }
}

// ---------------- LSTM recurrence via MFMA, weights resident in VGPRs ----------------
// grid 32 = dir(2) x slice(4) x bg(4); 512 threads (8 waves).
// Each wg: 256 gate rows (4 types x 64 hidden) x 8 batches; Whh slice held in
// VGPR A-fragments (bf16 hi+lo split for ~fp32 accuracy). h exchanged across the
// 4 wgs of a (dir,bg) group via packed u32 (bf16hi<<16|bf16lo) relaxed agent
// atomics + padded per-group counter; per-wave s_waitcnt vmcnt(0) before bump.
__launch_bounds__(512, 1)
__global__ void rec_k(const u16* __restrict__ G, const float* __restrict__ whh_l,
                      u32* __restrict__ Hbuf, int* __restrict__ cnt,
                      u16* __restrict__ Xbf, float* __restrict__ Xf) {
  __shared__ u16 hhi_lds[16][264];   // [batch(8 real+8 zero)][k=256 pad 264]
  __shared__ u16 hlo_lds[16][264];
  __shared__ float part[4 * 64 * 17]; // [type][jj][b pad17]
  __shared__ float clds[512];         // c state: [b][jj] = clds[tid]

  const int tid = threadIdx.x;
  const int dir = blockIdx.x >> 4;
  const int slice = (blockIdx.x >> 2) & 3;
  const int bg = blockIdx.x & 3;
  const int s64 = slice * 64;
  const int w = tid >> 6;
  const int lane = tid & 63;
  const int q = lane >> 4;      // quad
  const int lr = lane & 15;
  const int type = w >> 1;      // gate type for MFMA phase
  const int jjb = (w & 1) * 32; // hidden base within 64-slice

  const float* whh = whh_l + (size_t)dir * (1024 * 256);

  // ---- one-time: preload Whh slice into VGPR A-fragments (hi + lo residual) ----
  short8v Ahi[2][8], Alo[2][8];
  #pragma unroll
  for (int ti = 0; ti < 2; ++ti) {
    const float* wrow = whh + (size_t)(type * 256 + s64 + jjb + ti * 16 + lr) * 256;
    #pragma unroll
    for (int ks = 0; ks < 8; ++ks) {
      const float* pk = wrow + ks * 32 + q * 8;
      short8v hi, lo;
      #pragma unroll
      for (int j = 0; j < 8; ++j) {
        float v = pk[j];
        u16 hb = f2bf(v);
        hi[j] = (short)hb;
        lo[j] = (short)f2bf(v - bf2f(hb));
      }
      Ahi[ti][ks] = hi; Alo[ti][ks] = lo;
    }
  }
  for (int i = tid; i < 16 * 264; i += 512) {
    ((u16*)hhi_lds)[i] = 0; ((u16*)hlo_lds)[i] = 0;
  }
  clds[tid] = 0.f;

  int* mycnt = cnt + (dir * 4 + bg) * 16;
  u32* hb = Hbuf + (size_t)(dir * 4 + bg) * 4096;   // 2 parity * 2048 u32
  const int bu = w;       // updater: batch in group (0..7)
  const int ju = lane;    // updater: hidden in slice (0..63)
  __syncthreads();

  for (int st = 0; st < 512; ++st) {
    const int t = dir ? (511 - st) : st;
    const int par = st & 1;
    if (st > 0) {
      const int target = 32 * st;   // 4 wgs * 8 waves bump per step
      int spin = 0;
      while (__hip_atomic_load(mycnt, __ATOMIC_RELAXED, __HIP_MEMORY_SCOPE_AGENT) < target) {
        if (++spin > (1 << 20)) break;   // hang-avoidance only
      }
    }
    // G prefetch (consumed after B2; latency hidden by MFMA phase)
    const u16* gp = G + (size_t)(t * 32 + bg * 8 + bu) * 2048 + dir * 1024 + s64 + ju;
    u16 gv0 = gp[0], gv1 = gp[256], gv2 = gp[512], gv3 = gp[768];
    // h_prev: packed u32 loads -> unpack -> LDS (B-operand layout [b][k])
    if (st > 0) {
      const u64* src = (const u64*)(hb + par * 2048);
      u64 p0 = __hip_atomic_load(src + 2 * tid,     __ATOMIC_RELAXED, __HIP_MEMORY_SCOPE_AGENT);
      u64 p1 = __hip_atomic_load(src + 2 * tid + 1, __ATOMIC_RELAXED, __HIP_MEMORY_SCOPE_AGENT);
      u32 c0 = (u32)p0, c1 = (u32)(p0 >> 32), c2 = (u32)p1, c3 = (u32)(p1 >> 32);
      const int b = tid >> 6, k4 = (tid & 63) * 4;
      u64 hiq = (u64)(c0 >> 16) | ((u64)(c1 >> 16) << 16)
              | ((u64)(c2 >> 16) << 32) | ((u64)(c3 >> 16) << 48);
      u64 loq = (u64)(c0 & 0xffffu) | ((u64)(c1 & 0xffffu) << 16)
              | ((u64)(c2 & 0xffffu) << 32) | ((u64)(c3 & 0xffffu) << 48);
      *(u64*)&hhi_lds[b][k4] = hiq;
      *(u64*)&hlo_lds[b][k4] = loq;
    }
    __syncthreads();   // B1
    // MFMA phase: out[row][b] = W[row][:] . h[:][b]  (3-term hi/lo split)
    floatx4 acc0 = {0,0,0,0}, acc1 = {0,0,0,0};
    #pragma unroll
    for (int ks = 0; ks < 8; ++ks) {
      short8v bhi = *(const short8v*)&hhi_lds[lr][ks * 32 + q * 8];
      short8v blo = *(const short8v*)&hlo_lds[lr][ks * 32 + q * 8];
      acc0 = __builtin_amdgcn_mfma_f32_16x16x32_bf16(Ahi[0][ks], bhi, acc0, 0, 0, 0);
      acc1 = __builtin_amdgcn_mfma_f32_16x16x32_bf16(Ahi[1][ks], bhi, acc1, 0, 0, 0);
      acc0 = __builtin_amdgcn_mfma_f32_16x16x32_bf16(Alo[0][ks], bhi, acc0, 0, 0, 0);
      acc1 = __builtin_amdgcn_mfma_f32_16x16x32_bf16(Alo[1][ks], bhi, acc1, 0, 0, 0);
      acc0 = __builtin_amdgcn_mfma_f32_16x16x32_bf16(Ahi[0][ks], blo, acc0, 0, 0, 0);
      acc1 = __builtin_amdgcn_mfma_f32_16x16x32_bf16(Ahi[1][ks], blo, acc1, 0, 0, 0);
    }
    // C layout: col(b)=lane&15, row(jj)=quad*4+reg  [verified by passing gemm_k]
    #pragma unroll
    for (int reg = 0; reg < 4; ++reg) {
      part[(type * 64 + jjb +      q * 4 + reg) * 17 + lr] = acc0[reg];
      part[(type * 64 + jjb + 16 + q * 4 + reg) * 17 + lr] = acc1[reg];
    }
    __syncthreads();   // B2
    // updater phase: all 512 threads, one (b,jj) each
    {
      float si = bf2f(gv0) + part[(0 * 64 + ju) * 17 + bu];
      float sf = bf2f(gv1) + part[(1 * 64 + ju) * 17 + bu];
      float sg = bf2f(gv2) + part[(2 * 64 + ju) * 17 + bu];
      float so = bf2f(gv3) + part[(3 * 64 + ju) * 17 + bu];
      float cold = clds[tid];
      float ig = sigf(si), fg = sigf(sf), gg = tanh_f(sg), og = sigf(so);
      float cn = fg * cold + ig * gg;
      float hn = og * tanh_f(cn);
      clds[tid] = cn;
      u16 hhi = f2bf(hn);
      u16 hlo = f2bf(hn - bf2f(hhi));
      u32 hv = ((u32)hhi << 16) | hlo;
      __hip_atomic_store(hb + (par ^ 1) * 2048 + bu * 256 + s64 + ju, hv,
                         __ATOMIC_RELAXED, __HIP_MEMORY_SCOPE_AGENT);
      asm volatile("s_waitcnt vmcnt(0)" ::: "memory");   // drain h store
      if (lane == 0)
        __hip_atomic_fetch_add(mycnt, 1, __ATOMIC_RELAXED, __HIP_MEMORY_SCOPE_AGENT);
      // X output off the critical path (read only by a later dispatch)
      const size_t oidx = ((size_t)t * 32 + (bg * 8 + bu)) * 512 + dir * 256 + s64 + ju;
      if (Xbf) Xbf[oidx] = hhi;
      else     Xf[oidx] = hn;
    }
    // no end barrier: poll-exit for st+1 implies all waves bumped (i.e. finished
    // part reads), so next step's h_lds/part writes can't race.
  }
}

// ---------------- LayerNorm + classifier head; logits -> d_out+1 ----------------
__global__ void head_k(const float* __restrict__ X2, const float* __restrict__ gamma,
                       const float* __restrict__ beta, const float* __restrict__ cw,
                       const float* __restrict__ cb, float* __restrict__ out) {
  __shared__ float red[9][64];
  const int m = blockIdx.x, lane = threadIdx.x;
  const int s = m >> 5, b = m & 31;
  const float4* xp = (const float4*)(X2 + (size_t)m * 512) + lane * 2;
  float4 x0 = xp[0], x1 = xp[1];
  float sm = x0.x + x0.y + x0.z + x0.w + x1.x + x1.y + x1.z + x1.w;
  float sq = x0.x*x0.x + x0.y*x0.y + x0.z*x0.z + x0.w*x0.w
           + x1.x*x1.x + x1.y*x1.y + x1.z*x1.z + x1.w*x1.w;
  #pragma unroll
  for (int off = 32; off > 0; off >>= 1) {
    sm += __shfl_xor(sm, off, 64);
    sq += __shfl_xor(sq, off, 64);
  }
  const float mu = sm * (1.0f / 512.0f);
  const float var = sq * (1.0f / 512.0f) - mu * mu;
  const float rs = rsqrtf(var + 1e-5f);
  const float4* gp = (const float4*)gamma + lane * 2;
  const float4* bp = (const float4*)beta + lane * 2;
  float4 g0 = gp[0], g1 = gp[1], be0 = bp[0], be1 = bp[1];
  float nv[8];
  nv[0] = (x0.x - mu) * rs * g0.x + be0.x;
  nv[1] = (x0.y - mu) * rs * g0.y + be0.y;
  nv[2] = (x0.z - mu) * rs * g0.z + be0.z;
  nv[3] = (x0.w - mu) * rs * g0.w + be0.w;
  nv[4] = (x1.x - mu) * rs * g1.x + be1.x;
  nv[5] = (x1.y - mu) * rs * g1.y + be1.y;
  nv[6] = (x1.z - mu) * rs * g1.z + be1.z;
  nv[7] = (x1.w - mu) * rs * g1.w + be1.w;
  #pragma unroll
  for (int c = 0; c < 9; ++c) {
    const float4* wp = (const float4*)(cw + (size_t)c * 512) + lane * 2;
    float4 w0 = wp[0], w1 = wp[1];
    red[c][lane] = nv[0]*w0.x + nv[1]*w0.y + nv[2]*w0.z + nv[3]*w0.w
                 + nv[4]*w1.x + nv[5]*w1.y + nv[6]*w1.z + nv[7]*w1.w;
  }
  __syncthreads();
  if (lane < 9) {
    float t = 0.f;
    for (int i = 0; i < 64; ++i) t += red[lane][i];
    out[1 + ((size_t)b * 512 + s) * 9 + lane] = t + cb[lane];
  }
}

// ---------------- CRF NLL: one wave per batch element ----------------
__global__ void crf_k(const float* __restrict__ logits, const int* __restrict__ labels,
                      const int* __restrict__ lens, const float* __restrict__ tr,
                      float* __restrict__ loss) {
  const int b = blockIdx.x, lane = threadIdx.x;
  const int len = lens[b];
  float trj[9];
  #pragma unroll
  for (int i = 0; i < 9; ++i) trj[i] = 0.f;
  if (lane < 9) {
    #pragma unroll
    for (int i = 0; i < 9; ++i) trj[i] = tr[i * 11 + lane];
  }
  float alpha = -1e30f;
  if (lane < 9) alpha = tr[9 * 11 + lane] + logits[(size_t)b * 512 * 9 + lane];
  for (int t = 1; t < len; ++t) {
    float e = (lane < 9) ? logits[((size_t)b * 512 + t) * 9 + lane] : 0.f;
    float v[9];
    float mx = -1e30f;
    #pragma unroll
    for (int i = 0; i < 9; ++i) {
      v[i] = __shfl(alpha, i, 64) + trj[i];
      mx = fmaxf(mx, v[i]);
    }
    float ss = 0.f;
    #pragma unroll
    for (int i = 0; i < 9; ++i) ss += __expf(v[i] - mx);
    float na = mx + __logf(ss) + e;
    if (lane < 9) alpha = na;
  }
  float fin = (lane < 9) ? alpha + tr[lane * 11 + 10] : -1e30f;
  float mx = fin;
  #pragma unroll
  for (int off = 8; off > 0; off >>= 1) mx = fmaxf(mx, __shfl_xor(mx, off, 64));
  float es = (lane < 9) ? __expf(fin - mx) : 0.f;
  #pragma unroll
  for (int off = 8; off > 0; off >>= 1) es += __shfl_xor(es, off, 64);
  const float logZ = mx + __logf(es);
  float emit = 0.f, ts = 0.f;
  for (int t = lane; t < len; t += 64) {
    int y = labels[b * 512 + t];
    emit += logits[((size_t)b * 512 + t) * 9 + y];
  }
  for (int t = 1 + lane; t < len; t += 64) {
    int y0 = labels[b * 512 + t - 1], y1 = labels[b * 512 + t];
    ts += tr[y0 * 11 + y1];
  }
  #pragma unroll
  for (int off = 32; off > 0; off >>= 1) {
    emit += __shfl_xor(emit, off, 64);
    ts += __shfl_xor(ts, off, 64);
  }
  if (lane == 0) {
    int y0 = labels[b * 512], yl = labels[b * 512 + len - 1];
    float gold = emit + ts + tr[9 * 11 + y0] + tr[yl * 11 + 10];
    atomicAdd(loss, (logZ - gold) * (1.0f / 32.0f));
  }
}

extern "C" void kernel_launch(void* const* d_in, const int* in_sizes, int n_in,
                              void* d_out, int out_size, void* d_ws, size_t ws_size,
                              hipStream_t stream) {
  const int* ids = (const int*)d_in[0];
  const int* amask = (const int*)d_in[1];
  const int* lens = (const int*)d_in[2];
  const int* labels = (const int*)d_in[3];
  const float* emb = (const float*)d_in[4];
  const float* w_ih = (const float*)d_in[5];
  const float* w_hh = (const float*)d_in[6];
  const float* b_ih = (const float*)d_in[7];
  const float* b_hh = (const float*)d_in[8];
  const float* gamma = (const float*)d_in[9];
  const float* beta = (const float*)d_in[10];
  const float* cw = (const float*)d_in[11];
  const float* cb = (const float*)d_in[12];
  const float* tr = (const float*)d_in[13];
  (void)in_sizes; (void)n_in; (void)out_size;

  if (ws_size < WS_NEEDED) return;  // workspace too small -> clean failure

  char* p = (char*)d_ws;
  u16* X0 = (u16*)p;      p += (size_t)16384 * 512 * 2;        // 16.78 MB
  u16* Wbf = (u16*)p;     p += (size_t)2 * 2 * 1024 * 512 * 2; // 4.19 MB
  u16* G = (u16*)p;       p += (size_t)16384 * 2048 * 2;       // 67.1 MB
  u16* X1 = (u16*)p;      p += (size_t)16384 * 512 * 2;        // 16.78 MB
  float* X2 = (float*)p;  p += (size_t)16384 * 512 * 4;        // 33.55 MB
  u32* Hb = (u32*)p;      p += (size_t)32768 * 4;              // 128 KB
  int* cnt = (int*)p;     p += 512;
  float* out = (float*)d_out;

  prep_k<<<16384, 64, 0, stream>>>(ids, amask, emb, X0);
  conv_k<<<1024, 256, 0, stream>>>(w_ih, Wbf, 262144);
  zero_k<<<1, 64, 0, stream>>>(cnt, out);
  // Layer 0
  gemm_k<<<dim3(256, 32), 256, 0, stream>>>(X0, Wbf, b_ih, b_hh, G);
  rec_k<<<32, 512, 0, stream>>>(G, w_hh, Hb, cnt, X1, nullptr);
  zero_k<<<1, 64, 0, stream>>>(cnt, out);
  // Layer 1
  gemm_k<<<dim3(256, 32), 256, 0, stream>>>(X1, Wbf + 2 * 1024 * 512,
                                            b_ih + 2048, b_hh + 2048, G);
  rec_k<<<32, 512, 0, stream>>>(G, w_hh + 2 * 1024 * 256, Hb, cnt,
                                nullptr, X2);
  // Head + CRF
  head_k<<<16384, 64, 0, stream>>>(X2, gamma, beta, cw, cb, out);
  crf_k<<<32, 64, 0, stream>>>(out + 1, labels, lens, tr, out);
}

// Round 4
// 2931.576 us; speedup vs baseline: 8.1413x; 1.3604x over previous
//
#include <hip/hip_runtime.h>

// Problem dims
#define B_ 32
#define S_ 512
#define D_ 512
#define H_ 256

typedef float floatx4 __attribute__((ext_vector_type(4)));
typedef short short8v __attribute__((ext_vector_type(8)));
typedef unsigned short u16;
typedef unsigned int u32;
typedef unsigned long long u64;

#define WS_NEEDED 138544128ull

__device__ __forceinline__ u16 f2bf(float f) {
  u32 x = __float_as_uint(f);
  x += 0x7fffu + ((x >> 16) & 1u);   // RNE
  return (u16)(x >> 16);
}
__device__ __forceinline__ float bf2f(u16 h) {
  return __uint_as_float(((u32)h) << 16);
}
__device__ __forceinline__ float sigf(float x) {
  return 1.0f / (1.0f + __expf(-x));
}
__device__ __forceinline__ float tanh_f(float x) {
  float e = __expf(-2.0f * fabsf(x));
  float r = (1.0f - e) / (1.0f + e);
  return copysignf(r, x);
}

struct alignas(16) U16x8 { u16 v[8]; };

// ---------------- embedding -> X0 bf16, time-major (m = s*32+b, 512 feats) ----------------
__global__ void prep_k(const int* __restrict__ ids, const int* __restrict__ amask,
                       const float* __restrict__ emb, u16* __restrict__ X0) {
  int m = blockIdx.x;            // m = s*32 + b
  int lane = threadIdx.x;        // 64
  int s = m >> 5, b = m & 31;
  int id = ids[b * S_ + s];
  int mk = amask[b * S_ + s];
  const float4* src = (const float4*)(emb + (size_t)id * D_) + lane * 2;
  float4 v0 = src[0], v1 = src[1];
  if (!mk) { v0 = make_float4(0,0,0,0); v1 = make_float4(0,0,0,0); }
  U16x8 o;
  o.v[0]=f2bf(v0.x); o.v[1]=f2bf(v0.y); o.v[2]=f2bf(v0.z); o.v[3]=f2bf(v0.w);
  o.v[4]=f2bf(v1.x); o.v[5]=f2bf(v1.y); o.v[6]=f2bf(v1.z); o.v[7]=f2bf(v1.w);
  *(U16x8*)(X0 + (size_t)m * D_ + lane * 8) = o;
}

// ---------------- fp32 -> bf16 weight convert (w_ih, 2*2*1024*512 elems) ----------------
__global__ void conv_k(const float* __restrict__ w, u16* __restrict__ wbf, int n8) {
  int idx = blockIdx.x * blockDim.x + threadIdx.x;
  if (idx >= n8) return;
  const float4* s = (const float4*)w + (size_t)idx * 2;
  float4 v0 = s[0], v1 = s[1];
  U16x8 o;
  o.v[0]=f2bf(v0.x); o.v[1]=f2bf(v0.y); o.v[2]=f2bf(v0.z); o.v[3]=f2bf(v0.w);
  o.v[4]=f2bf(v1.x); o.v[5]=f2bf(v1.y); o.v[6]=f2bf(v1.z); o.v[7]=f2bf(v1.w);
  *(U16x8*)(wbf + (size_t)idx * 8) = o;
}

// ---------------- zero sync flags / loss ----------------
// flags: 8 groups x 32 ints (128B-spaced lines; first 4 ints of each used)
__global__ void zero_k(int* __restrict__ flg, float* __restrict__ loss) {
  int idx = threadIdx.x;
  if (idx < 256) flg[idx] = 0;
  if (idx == 0) *loss = 0.f;
}

// ---------------- bf16 MFMA GEMM: G[m][n] = A[m][:] . W[n][:] + bih[n] + bhh[n] ----------------
__global__ void gemm_k(const u16* __restrict__ A, const u16* __restrict__ W,
                       const float* __restrict__ bih, const float* __restrict__ bhh,
                       u16* __restrict__ G) {
  __shared__ short Asm[64 * 40];
  __shared__ short Bsm[64 * 40];
  const int tid = threadIdx.x;
  const int m0 = blockIdx.x * 64, n0 = blockIdx.y * 64;
  const int wid = tid >> 6, lane = tid & 63;
  const int quad = lane >> 4, lr = lane & 15;
  const int wm = (wid >> 1) * 32, wn = (wid & 1) * 32;
  const int lrow = tid >> 2, lk = (tid & 3) * 8;
  floatx4 acc00 = {0,0,0,0}, acc01 = {0,0,0,0}, acc10 = {0,0,0,0}, acc11 = {0,0,0,0};
  for (int kt = 0; kt < 16; ++kt) {
    const int k0 = kt * 32;
    uint4 av = *(const uint4*)(A + (size_t)(m0 + lrow) * 512 + k0 + lk);
    uint4 bv = *(const uint4*)(W + (size_t)(n0 + lrow) * 512 + k0 + lk);
    __syncthreads();
    *(uint4*)&Asm[lrow * 40 + lk] = av;
    *(uint4*)&Bsm[lrow * 40 + lk] = bv;
    __syncthreads();
    short8v a0 = *(const short8v*)&Asm[(wm + lr) * 40 + quad * 8];
    short8v a1 = *(const short8v*)&Asm[(wm + 16 + lr) * 40 + quad * 8];
    short8v b0 = *(const short8v*)&Bsm[(wn + lr) * 40 + quad * 8];
    short8v b1 = *(const short8v*)&Bsm[(wn + 16 + lr) * 40 + quad * 8];
    acc00 = __builtin_amdgcn_mfma_f32_16x16x32_bf16(a0, b0, acc00, 0, 0, 0);
    acc01 = __builtin_amdgcn_mfma_f32_16x16x32_bf16(a0, b1, acc01, 0, 0, 0);
    acc10 = __builtin_amdgcn_mfma_f32_16x16x32_bf16(a1, b0, acc10, 0, 0, 0);
    acc11 = __builtin_amdgcn_mfma_f32_16x16x32_bf16(a1, b1, acc11, 0, 0, 0);
  }
  #pragma unroll
  for (int j = 0; j < 2; ++j) {
    const int n = n0 + wn + j * 16 + lr;
    const float bias = bih[n] + bhh[n];
    #pragma unroll
    for (int i = 0; i < 2; ++i) {
      const int mb = m0 + wm + i * 16 + quad * 4;
      floatx4 av = (i == 0) ? (j == 0 ? acc00 : acc01) : (j == 0 ? acc10 : acc11);
      #pragma unroll
      for (int rr = 0; rr < 4; ++rr) {
        G[(size_t)(mb + rr) * 2048 + n] = f2bf(av[rr] + bias);
      }
    }
  }
}

// ---------------- LSTM recurrence via MFMA, weights resident in VGPRs ----------------
// grid 32 = dir(2) x slice(4) x bg(4); 512 threads (8 waves).
// Sync per step: producer stores h (relaxed agent), __syncthreads (drains vmcnt),
// ONE tid0 flag store per wg (NO RMWs); consumer polls the group's 4 flag words
// with two u64 relaxed loads. X output deferred past the flag store.
__launch_bounds__(512, 1)
__global__ void rec_k(const u16* __restrict__ G, const float* __restrict__ whh_l,
                      u32* __restrict__ Hbuf, int* __restrict__ flg,
                      u16* __restrict__ Xbf, float* __restrict__ Xf) {
  __shared__ u16 hhi_lds[16][264];   // [batch(8 real+8 zero)][k=256 pad 264]
  __shared__ u16 hlo_lds[16][264];
  __shared__ float part[4 * 64 * 17]; // [type][jj][b pad17]
  __shared__ float clds[512];         // c state: [b][jj] = clds[tid]

  const int tid = threadIdx.x;
  const int dir = blockIdx.x >> 4;
  const int slice = (blockIdx.x >> 2) & 3;
  const int bg = blockIdx.x & 3;
  const int s64 = slice * 64;
  const int w = tid >> 6;
  const int lane = tid & 63;
  const int q = lane >> 4;      // quad
  const int lr = lane & 15;
  const int type = w >> 1;      // gate type for MFMA phase
  const int jjb = (w & 1) * 32; // hidden base within 64-slice

  const float* whh = whh_l + (size_t)dir * (1024 * 256);

  // ---- one-time: preload Whh slice into VGPR A-fragments (hi + lo residual) ----
  short8v Ahi[2][8], Alo[2][8];
  #pragma unroll
  for (int ti = 0; ti < 2; ++ti) {
    const float* wrow = whh + (size_t)(type * 256 + s64 + jjb + ti * 16 + lr) * 256;
    #pragma unroll
    for (int ks = 0; ks < 8; ++ks) {
      const float* pk = wrow + ks * 32 + q * 8;
      short8v hi, lo;
      #pragma unroll
      for (int j = 0; j < 8; ++j) {
        float v = pk[j];
        u16 hb = f2bf(v);
        hi[j] = (short)hb;
        lo[j] = (short)f2bf(v - bf2f(hb));
      }
      Ahi[ti][ks] = hi; Alo[ti][ks] = lo;
    }
  }
  for (int i = tid; i < 16 * 264; i += 512) {
    ((u16*)hhi_lds)[i] = 0; ((u16*)hlo_lds)[i] = 0;
  }
  clds[tid] = 0.f;

  int* flags = flg + (dir * 4 + bg) * 32;           // 128B line per group
  u32* hb = Hbuf + (size_t)(dir * 4 + bg) * 4096;   // 2 parity * 2048 u32
  const int bu = w;       // updater: batch in group (0..7)
  const int ju = lane;    // updater: hidden in slice (0..63)
  __syncthreads();

  for (int st = 0; st < 512; ++st) {
    const int t = dir ? (511 - st) : st;
    const int par = st & 1;
    if (st > 0) {
      const u32 target = (u32)st;
      const u64* f64 = (const u64*)flags;
      int spin = 0;
      for (;;) {
        u64 a = __hip_atomic_load(f64,     __ATOMIC_RELAXED, __HIP_MEMORY_SCOPE_AGENT);
        u64 b = __hip_atomic_load(f64 + 1, __ATOMIC_RELAXED, __HIP_MEMORY_SCOPE_AGENT);
        u32 f0 = (u32)a, f1 = (u32)(a >> 32), f2 = (u32)b, f3 = (u32)(b >> 32);
        if (f0 >= target && f1 >= target && f2 >= target && f3 >= target) break;
        if (++spin > (1 << 20)) break;   // hang-avoidance only
      }
    }
    // G prefetch (consumed after B2; latency hidden under h-load/MFMA)
    const u16* gp = G + (size_t)(t * 32 + bg * 8 + bu) * 2048 + dir * 1024 + s64 + ju;
    u16 gv0 = gp[0], gv1 = gp[256], gv2 = gp[512], gv3 = gp[768];
    // h_prev: packed u32 loads -> unpack -> LDS (B-operand layout [b][k])
    if (st > 0) {
      const u64* src = (const u64*)(hb + par * 2048);
      u64 p0 = __hip_atomic_load(src + 2 * tid,     __ATOMIC_RELAXED, __HIP_MEMORY_SCOPE_AGENT);
      u64 p1 = __hip_atomic_load(src + 2 * tid + 1, __ATOMIC_RELAXED, __HIP_MEMORY_SCOPE_AGENT);
      u32 c0 = (u32)p0, c1 = (u32)(p0 >> 32), c2 = (u32)p1, c3 = (u32)(p1 >> 32);
      const int b = tid >> 6, k4 = (tid & 63) * 4;
      u64 hiq = (u64)(c0 >> 16) | ((u64)(c1 >> 16) << 16)
              | ((u64)(c2 >> 16) << 32) | ((u64)(c3 >> 16) << 48);
      u64 loq = (u64)(c0 & 0xffffu) | ((u64)(c1 & 0xffffu) << 16)
              | ((u64)(c2 & 0xffffu) << 32) | ((u64)(c3 & 0xffffu) << 48);
      *(u64*)&hhi_lds[b][k4] = hiq;
      *(u64*)&hlo_lds[b][k4] = loq;
    }
    __syncthreads();   // B1
    // MFMA phase: out[row][b] = W[row][:] . h[:][b]  (3-term hi/lo split)
    floatx4 acc0 = {0,0,0,0}, acc1 = {0,0,0,0};
    #pragma unroll
    for (int ks = 0; ks < 8; ++ks) {
      short8v bhi = *(const short8v*)&hhi_lds[lr][ks * 32 + q * 8];
      short8v blo = *(const short8v*)&hlo_lds[lr][ks * 32 + q * 8];
      acc0 = __builtin_amdgcn_mfma_f32_16x16x32_bf16(Ahi[0][ks], bhi, acc0, 0, 0, 0);
      acc1 = __builtin_amdgcn_mfma_f32_16x16x32_bf16(Ahi[1][ks], bhi, acc1, 0, 0, 0);
      acc0 = __builtin_amdgcn_mfma_f32_16x16x32_bf16(Alo[0][ks], bhi, acc0, 0, 0, 0);
      acc1 = __builtin_amdgcn_mfma_f32_16x16x32_bf16(Alo[1][ks], bhi, acc1, 0, 0, 0);
      acc0 = __builtin_amdgcn_mfma_f32_16x16x32_bf16(Ahi[0][ks], blo, acc0, 0, 0, 0);
      acc1 = __builtin_amdgcn_mfma_f32_16x16x32_bf16(Ahi[1][ks], blo, acc1, 0, 0, 0);
    }
    // C layout: col(b)=lane&15, row(jj)=quad*4+reg
    #pragma unroll
    for (int reg = 0; reg < 4; ++reg) {
      part[(type * 64 + jjb +      q * 4 + reg) * 17 + lr] = acc0[reg];
      part[(type * 64 + jjb + 16 + q * 4 + reg) * 17 + lr] = acc1[reg];
    }
    __syncthreads();   // B2
    // updater phase: all 512 threads, one (b,jj) each
    float si = bf2f(gv0) + part[(0 * 64 + ju) * 17 + bu];
    float sf = bf2f(gv1) + part[(1 * 64 + ju) * 17 + bu];
    float sg = bf2f(gv2) + part[(2 * 64 + ju) * 17 + bu];
    float so = bf2f(gv3) + part[(3 * 64 + ju) * 17 + bu];
    float cold = clds[tid];
    float ig = sigf(si), fg = sigf(sf), gg = tanh_f(sg), og = sigf(so);
    float cn = fg * cold + ig * gg;
    float hn = og * tanh_f(cn);
    clds[tid] = cn;
    u16 hhi = f2bf(hn);
    u16 hlo = f2bf(hn - bf2f(hhi));
    u32 hv = ((u32)hhi << 16) | hlo;
    __hip_atomic_store(hb + (par ^ 1) * 2048 + bu * 256 + s64 + ju, hv,
                       __ATOMIC_RELAXED, __HIP_MEMORY_SCOPE_AGENT);
    __syncthreads();   // B3: built-in s_waitcnt vmcnt(0) drains ALL waves' h stores
    if (tid == 0)
      __hip_atomic_store((u32*)&flags[slice], (u32)(st + 1),
                         __ATOMIC_RELAXED, __HIP_MEMORY_SCOPE_AGENT);
    // X output deferred past the flag store (off the critical path)
    const size_t oidx = ((size_t)t * 32 + (bg * 8 + bu)) * 512 + dir * 256 + s64 + ju;
    if (Xbf) Xbf[oidx] = hhi;
    else     Xf[oidx] = hn;
  }
}

// ---------------- LayerNorm + classifier head; logits -> d_out+1 ----------------
__global__ void head_k(const float* __restrict__ X2, const float* __restrict__ gamma,
                       const float* __restrict__ beta, const float* __restrict__ cw,
                       const float* __restrict__ cb, float* __restrict__ out) {
  __shared__ float red[9][64];
  const int m = blockIdx.x, lane = threadIdx.x;
  const int s = m >> 5, b = m & 31;
  const float4* xp = (const float4*)(X2 + (size_t)m * 512) + lane * 2;
  float4 x0 = xp[0], x1 = xp[1];
  float sm = x0.x + x0.y + x0.z + x0.w + x1.x + x1.y + x1.z + x1.w;
  float sq = x0.x*x0.x + x0.y*x0.y + x0.z*x0.z + x0.w*x0.w
           + x1.x*x1.x + x1.y*x1.y + x1.z*x1.z + x1.w*x1.w;
  #pragma unroll
  for (int off = 32; off > 0; off >>= 1) {
    sm += __shfl_xor(sm, off, 64);
    sq += __shfl_xor(sq, off, 64);
  }
  const float mu = sm * (1.0f / 512.0f);
  const float var = sq * (1.0f / 512.0f) - mu * mu;
  const float rs = rsqrtf(var + 1e-5f);
  const float4* gp = (const float4*)gamma + lane * 2;
  const float4* bp = (const float4*)beta + lane * 2;
  float4 g0 = gp[0], g1 = gp[1], be0 = bp[0], be1 = bp[1];
  float nv[8];
  nv[0] = (x0.x - mu) * rs * g0.x + be0.x;
  nv[1] = (x0.y - mu) * rs * g0.y + be0.y;
  nv[2] = (x0.z - mu) * rs * g0.z + be0.z;
  nv[3] = (x0.w - mu) * rs * g0.w + be0.w;
  nv[4] = (x1.x - mu) * rs * g1.x + be1.x;
  nv[5] = (x1.y - mu) * rs * g1.y + be1.y;
  nv[6] = (x1.z - mu) * rs * g1.z + be1.z;
  nv[7] = (x1.w - mu) * rs * g1.w + be1.w;
  #pragma unroll
  for (int c = 0; c < 9; ++c) {
    const float4* wp = (const float4*)(cw + (size_t)c * 512) + lane * 2;
    float4 w0 = wp[0], w1 = wp[1];
    red[c][lane] = nv[0]*w0.x + nv[1]*w0.y + nv[2]*w0.z + nv[3]*w0.w
                 + nv[4]*w1.x + nv[5]*w1.y + nv[6]*w1.z + nv[7]*w1.w;
  }
  __syncthreads();
  if (lane < 9) {
    float t = 0.f;
    for (int i = 0; i < 64; ++i) t += red[lane][i];
    out[1 + ((size_t)b * 512 + s) * 9 + lane] = t + cb[lane];
  }
}

// ---------------- CRF NLL: one wave per batch element ----------------
__global__ void crf_k(const float* __restrict__ logits, const int* __restrict__ labels,
                      const int* __restrict__ lens, const float* __restrict__ tr,
                      float* __restrict__ loss) {
  const int b = blockIdx.x, lane = threadIdx.x;
  const int len = lens[b];
  float trj[9];
  #pragma unroll
  for (int i = 0; i < 9; ++i) trj[i] = 0.f;
  if (lane < 9) {
    #pragma unroll
    for (int i = 0; i < 9; ++i) trj[i] = tr[i * 11 + lane];
  }
  float alpha = -1e30f;
  if (lane < 9) alpha = tr[9 * 11 + lane] + logits[(size_t)b * 512 * 9 + lane];
  for (int t = 1; t < len; ++t) {
    float e = (lane < 9) ? logits[((size_t)b * 512 + t) * 9 + lane] : 0.f;
    float v[9];
    float mx = -1e30f;
    #pragma unroll
    for (int i = 0; i < 9; ++i) {
      v[i] = __shfl(alpha, i, 64) + trj[i];
      mx = fmaxf(mx, v[i]);
    }
    float ss = 0.f;
    #pragma unroll
    for (int i = 0; i < 9; ++i) ss += __expf(v[i] - mx);
    float na = mx + __logf(ss) + e;
    if (lane < 9) alpha = na;
  }
  float fin = (lane < 9) ? alpha + tr[lane * 11 + 10] : -1e30f;
  float mx = fin;
  #pragma unroll
  for (int off = 8; off > 0; off >>= 1) mx = fmaxf(mx, __shfl_xor(mx, off, 64));
  float es = (lane < 9) ? __expf(fin - mx) : 0.f;
  #pragma unroll
  for (int off = 8; off > 0; off >>= 1) es += __shfl_xor(es, off, 64);
  const float logZ = mx + __logf(es);
  float emit = 0.f, ts = 0.f;
  for (int t = lane; t < len; t += 64) {
    int y = labels[b * 512 + t];
    emit += logits[((size_t)b * 512 + t) * 9 + y];
  }
  for (int t = 1 + lane; t < len; t += 64) {
    int y0 = labels[b * 512 + t - 1], y1 = labels[b * 512 + t];
    ts += tr[y0 * 11 + y1];
  }
  #pragma unroll
  for (int off = 32; off > 0; off >>= 1) {
    emit += __shfl_xor(emit, off, 64);
    ts += __shfl_xor(ts, off, 64);
  }
  if (lane == 0) {
    int y0 = labels[b * 512], yl = labels[b * 512 + len - 1];
    float gold = emit + ts + tr[9 * 11 + y0] + tr[yl * 11 + 10];
    atomicAdd(loss, (logZ - gold) * (1.0f / 32.0f));
  }
}

extern "C" void kernel_launch(void* const* d_in, const int* in_sizes, int n_in,
                              void* d_out, int out_size, void* d_ws, size_t ws_size,
                              hipStream_t stream) {
  const int* ids = (const int*)d_in[0];
  const int* amask = (const int*)d_in[1];
  const int* lens = (const int*)d_in[2];
  const int* labels = (const int*)d_in[3];
  const float* emb = (const float*)d_in[4];
  const float* w_ih = (const float*)d_in[5];
  const float* w_hh = (const float*)d_in[6];
  const float* b_ih = (const float*)d_in[7];
  const float* b_hh = (const float*)d_in[8];
  const float* gamma = (const float*)d_in[9];
  const float* beta = (const float*)d_in[10];
  const float* cw = (const float*)d_in[11];
  const float* cb = (const float*)d_in[12];
  const float* tr = (const float*)d_in[13];
  (void)in_sizes; (void)n_in; (void)out_size;

  if (ws_size < WS_NEEDED) return;  // workspace too small -> clean failure

  char* p = (char*)d_ws;
  u16* X0 = (u16*)p;      p += (size_t)16384 * 512 * 2;        // 16.78 MB
  u16* Wbf = (u16*)p;     p += (size_t)2 * 2 * 1024 * 512 * 2; // 4.19 MB
  u16* G = (u16*)p;       p += (size_t)16384 * 2048 * 2;       // 67.1 MB
  u16* X1 = (u16*)p;      p += (size_t)16384 * 512 * 2;        // 16.78 MB
  float* X2 = (float*)p;  p += (size_t)16384 * 512 * 4;        // 33.55 MB
  u32* Hb = (u32*)p;      p += (size_t)32768 * 4;              // 128 KB
  int* flg = (int*)p;     p += 1024;                           // 8 groups x 128B
  float* out = (float*)d_out;

  prep_k<<<16384, 64, 0, stream>>>(ids, amask, emb, X0);
  conv_k<<<1024, 256, 0, stream>>>(w_ih, Wbf, 262144);
  zero_k<<<1, 256, 0, stream>>>(flg, out);
  // Layer 0
  gemm_k<<<dim3(256, 32), 256, 0, stream>>>(X0, Wbf, b_ih, b_hh, G);
  rec_k<<<32, 512, 0, stream>>>(G, w_hh, Hb, flg, X1, nullptr);
  zero_k<<<1, 256, 0, stream>>>(flg, out);
  // Layer 1
  gemm_k<<<dim3(256, 32), 256, 0, stream>>>(X1, Wbf + 2 * 1024 * 512,
                                            b_ih + 2048, b_hh + 2048, G);
  rec_k<<<32, 512, 0, stream>>>(G, w_hh + 2 * 1024 * 256, Hb, flg,
                                nullptr, X2);
  // Head + CRF
  head_k<<<16384, 64, 0, stream>>>(X2, gamma, beta, cw, cb, out);
  crf_k<<<32, 64, 0, stream>>>(out + 1, labels, lens, tr, out);
}